// Round 10
// baseline (535.669 us; speedup 1.0000x reference)
//
#include <hip/hip_runtime.h>
#include <hip/hip_bf16.h>

#define B_ 2
#define T_ 2048
#define D_ 1024
#define H_ 16

typedef __attribute__((ext_vector_type(8))) short bf16x8;
typedef __attribute__((ext_vector_type(4))) float f32x4;

__device__ __forceinline__ unsigned pack_bf16(float x, float y) {
  unsigned xb = __float_as_uint(x), yb = __float_as_uint(y);
  xb += 0x7fffu + ((xb >> 16) & 1u);
  yb += 0x7fffu + ((yb >> 16) & 1u);
  return (xb >> 16) | (yb & 0xffff0000u);
}
__device__ __forceinline__ unsigned short f2b(float x) {
  unsigned u = __float_as_uint(x);
  u += 0x7fffu + ((u >> 16) & 1u);
  return (unsigned short)(u >> 16);
}
__device__ __forceinline__ float blo(unsigned u) { return __uint_as_float(u << 16); }
__device__ __forceinline__ float bhi(unsigned u) { return __uint_as_float(u & 0xffff0000u); }

__device__ __forceinline__ void gld_lds16(const unsigned short* g, unsigned short* l) {
  __builtin_amdgcn_global_load_lds(
      (const __attribute__((address_space(1))) unsigned int*)g,
      (__attribute__((address_space(3))) unsigned int*)l, 16, 0, 0);
}

// ---------- weight transpose + convert: Wt[n][k] = bf16(W[k][n]), 4 weights ----------
__global__ __launch_bounds__(256) void wtrans(const float* __restrict__ W0, const float* __restrict__ W1,
                                              const float* __restrict__ W2, const float* __restrict__ W3,
                                              unsigned short* __restrict__ T0, unsigned short* __restrict__ T1,
                                              unsigned short* __restrict__ T2, unsigned short* __restrict__ T3) {
  const int z = blockIdx.z;
  const float* W = z == 0 ? W0 : z == 1 ? W1 : z == 2 ? W2 : W3;
  unsigned short* T = z == 0 ? T0 : z == 1 ? T1 : z == 2 ? T2 : T3;
  __shared__ unsigned short t[64][72];
  const int k0 = blockIdx.x << 6, n0 = blockIdx.y << 6;
  const int r = threadIdx.x >> 2, c16 = (threadIdx.x & 3) << 4;
#pragma unroll
  for (int e = 0; e < 4; ++e) {
    const float4 v = *(const float4*)&W[(size_t)(k0 + r) * 1024 + n0 + c16 + e * 4];
    t[r][c16 + e * 4 + 0] = f2b(v.x);
    t[r][c16 + e * 4 + 1] = f2b(v.y);
    t[r][c16 + e * 4 + 2] = f2b(v.z);
    t[r][c16 + e * 4 + 3] = f2b(v.w);
  }
  __syncthreads();
  unsigned short o[16];
#pragma unroll
  for (int e = 0; e < 16; ++e) o[e] = t[c16 + e][r];
  unsigned short* dst = &T[(size_t)(n0 + r) * 1024 + k0 + c16];
  *(uint4*)&dst[0] = *(uint4*)&o[0];
  *(uint4*)&dst[8] = *(uint4*)&o[8];
}

// ---------- x fp32 -> bf16 ----------
__global__ __launch_bounds__(256) void xconv(const float* __restrict__ x, unsigned short* __restrict__ xb) {
  const int i = (blockIdx.x * 256 + threadIdx.x) * 8;
  const float4 a = *(const float4*)&x[i];
  const float4 b = *(const float4*)&x[i + 4];
  uint4 o;
  o.x = pack_bf16(a.x, a.y);
  o.y = pack_bf16(a.z, a.w);
  o.z = pack_bf16(b.x, b.y);
  o.w = pack_bf16(b.z, b.w);
  *(uint4*)&xb[i] = o;
}

// ---------- bf16 MFMA GEMM: Y = A[M,1024] @ Bt[n][k]^T + bias ----------
template <bool BF16OUT>
__global__ __launch_bounds__(256) void gemm_mfma(const unsigned short* __restrict__ A,
                                                 const unsigned short* __restrict__ B0,
                                                 const unsigned short* __restrict__ B1,
                                                 const unsigned short* __restrict__ B2,
                                                 const float* __restrict__ bi0, const float* __restrict__ bi1,
                                                 const float* __restrict__ bi2,
                                                 void* __restrict__ Y0, void* __restrict__ Y1,
                                                 void* __restrict__ Y2) {
  const int z = blockIdx.z;
  const unsigned short* Bt = z == 0 ? B0 : z == 1 ? B1 : B2;
  const float* bias = z == 0 ? bi0 : z == 1 ? bi1 : bi2;
  void* Y = z == 0 ? Y0 : z == 1 ? Y1 : Y2;
  __shared__ unsigned short As[8192];
  __shared__ unsigned short Bs[8192];
  const int tid = threadIdx.x;
  const int m0 = blockIdx.y << 7, n0 = blockIdx.x << 7;
  const int w = tid >> 6, l = tid & 63, g = l >> 4, c = l & 15;
  const int wm = (w >> 1) << 6, wn = (w & 1) << 6;
  const int srow = tid >> 3;
  const int skel = ((tid & 7) ^ (srow & 7)) << 3;
  const unsigned short* ga = &A[(size_t)(m0 + srow) * 1024 + skel];
  const unsigned short* gb = &Bt[(size_t)(n0 + srow) * 1024 + skel];
  unsigned short* la = &As[tid << 3];
  unsigned short* lb = &Bs[tid << 3];
  f32x4 acc[4][4];
#pragma unroll
  for (int i = 0; i < 4; ++i)
#pragma unroll
    for (int j = 0; j < 4; ++j) acc[i][j] = {0.f, 0.f, 0.f, 0.f};
  for (int k0 = 0; k0 < 1024; k0 += 64) {
    __syncthreads();
#pragma unroll
    for (int a = 0; a < 4; ++a) {
      gld_lds16(ga + (size_t)(a << 5) * 1024 + k0, la + (a << 11));
      gld_lds16(gb + (size_t)(a << 5) * 1024 + k0, lb + (a << 11));
    }
    __syncthreads();
#pragma unroll
    for (int kc = 0; kc < 2; ++kc) {
      bf16x8 af[4], bfr[4];
#pragma unroll
      for (int mf = 0; mf < 4; ++mf) {
        const int m = wm + (mf << 4) + c;
        af[mf] = *(const bf16x8*)&As[((m << 6) + (kc << 5) + (g << 3)) ^ ((m & 7) << 3)];
      }
#pragma unroll
      for (int nf = 0; nf < 4; ++nf) {
        const int n = wn + (nf << 4) + c;
        bfr[nf] = *(const bf16x8*)&Bs[((n << 6) + (kc << 5) + (g << 3)) ^ ((n & 7) << 3)];
      }
#pragma unroll
      for (int mf = 0; mf < 4; ++mf)
#pragma unroll
        for (int nf = 0; nf < 4; ++nf)
          acc[mf][nf] = __builtin_amdgcn_mfma_f32_16x16x32_bf16(af[mf], bfr[nf], acc[mf][nf], 0, 0, 0);
    }
  }
#pragma unroll
  for (int nf = 0; nf < 4; ++nf) {
    const int n = n0 + wn + (nf << 4) + c;
    const float bb = bias[n];
#pragma unroll
    for (int mf = 0; mf < 4; ++mf) {
      const int mrow = m0 + wm + (mf << 4) + (g << 2);
#pragma unroll
      for (int r = 0; r < 4; ++r) {
        const float val = acc[mf][nf][r] + bb;
        if (BF16OUT)
          ((unsigned short*)Y)[((size_t)(mrow + r) << 10) + n] = f2b(val);
        else
          ((float*)Y)[((size_t)(mrow + r) << 10) + n] = val;
      }
    }
  }
}

// ---------- bf16 transpose: Vb [b][t][d] -> Vt [b][d][t] ----------
__global__ __launch_bounds__(256) void transpose_bf16(const unsigned short* __restrict__ Vb,
                                                      unsigned short* __restrict__ Vt) {
  __shared__ unsigned short tile[64][73];
  const int b = blockIdx.z;
  const int t0 = blockIdx.x << 6, d0 = blockIdx.y << 6;
  const int row = threadIdx.x >> 2, cq = (threadIdx.x & 3) << 4;
  const unsigned short* src = &Vb[((size_t)((b << 11) + t0 + row) << 10) + d0 + cq];
  const uint4 va = *(const uint4*)&src[0];
  const uint4 vb2 = *(const uint4*)&src[8];
  const unsigned in[8] = {va.x, va.y, va.z, va.w, vb2.x, vb2.y, vb2.z, vb2.w};
#pragma unroll
  for (int e = 0; e < 8; ++e) {
    tile[row][cq + 2 * e] = (unsigned short)in[e];
    tile[row][cq + 2 * e + 1] = (unsigned short)(in[e] >> 16);
  }
  __syncthreads();
  unsigned o[8];
#pragma unroll
  for (int e = 0; e < 8; ++e)
    o[e] = (unsigned)tile[cq + 2 * e][row] | ((unsigned)tile[cq + 2 * e + 1][row] << 16);
  unsigned short* dst = &Vt[((size_t)((b << 10) + d0 + row) << 11) + t0 + cq];
  uint4 lo, hi;
  lo.x = o[0]; lo.y = o[1]; lo.z = o[2]; lo.w = o[3];
  hi.x = o[4]; hi.y = o[5]; hi.z = o[6]; hi.w = o[7];
  *(uint4*)&dst[0] = lo;
  *(uint4*)&dst[8] = hi;
}

// ---------- per-32-row block sums of V ----------
__global__ __launch_bounds__(256) void vblk32(const unsigned short* __restrict__ Vb,
                                              float* __restrict__ Blk) {
  const int b = blockIdx.x >> 6, t = blockIdx.x & 63;
  const int d4 = threadIdx.x << 2;
  float s0 = 0.f, s1 = 0.f, s2 = 0.f, s3 = 0.f;
  for (int j = 0; j < 32; ++j) {
    const uint2 v = *(const uint2*)&Vb[((size_t)((b << 11) + (t << 5) + j) << 10) + d4];
    s0 += blo(v.x); s1 += bhi(v.x); s2 += blo(v.y); s3 += bhi(v.y);
  }
  float4 o = {s0, s1, s2, s3};
  *(float4*)&Blk[((size_t)((b << 6) + t) << 10) + d4] = o;
}

// ---------- suffix over 64 tiles ----------
__global__ __launch_bounds__(256) void vsuffix32(const float* __restrict__ Blk, float* __restrict__ Suf) {
  const int idx = blockIdx.x * 256 + threadIdx.x;
  const int b = idx >> 10, d = idx & 1023;
  float s = 0.f;
  Suf[((size_t)(b * 65 + 64) << 10) + d] = 0.f;
  for (int t = 63; t >= 0; --t) {
    s += Blk[((size_t)((b << 6) + t) << 10) + d];
    Suf[((size_t)(b * 65 + t) << 10) + d] = s;
  }
}

// ---------- attention v10: 64-j fat steps (half the barriers of v9) ----------
// Block = 8 waves, complementary tile pair (y, 127-y). Per 64-j step: 4 QK sub-tiles
// (16 K loads in flight), exp packed to bf16 across ONE Sigma-exp exchange, then two
// 32-j PV chunks (chunk B's V loaded post-barrier into reused regs). Strip partials.
__global__ __launch_bounds__(512, 4) void attn_v10(const unsigned short* __restrict__ Qb,
                                                   const unsigned short* __restrict__ Kb,
                                                   const unsigned short* __restrict__ Vt,
                                                   unsigned short* __restrict__ P0,
                                                   unsigned short* __restrict__ P1,
                                                   unsigned short* __restrict__ P2,
                                                   unsigned short* __restrict__ P3) {
  __shared__ f32x4 Sx[2][8][4][64];  // 64 KB double-buffered exchange (4 j-subtiles)

  const int s = blockIdx.x;
  const int y = blockIdx.y;
  const int b = blockIdx.z;
  const int tid = threadIdx.x;
  const int w = tid >> 6, l = tid & 63, g = l >> 4, c = l & 15;
  const float SC = 0.04508422f;  // log2(e)/32
  unsigned short* AOp = s == 0 ? P0 : s == 1 ? P1 : s == 2 ? P2 : P3;

  int buf = 0;
#pragma unroll
  for (int phase = 0; phase < 2; ++phase) {
    const int it = phase ? (127 - y) : y;
    const int nt = (it >> 2) + 1;  // 64-j steps covering diagonal
    const int i0 = it << 4;
    const int ib = i0 + c;

    const unsigned short* qbase = &Qb[((size_t)((b << 11) + i0 + c) << 10) + (w << 7) + (g << 3)];
    bf16x8 qf[4];
    qf[0] = *(const bf16x8*)&qbase[0];
    qf[1] = *(const bf16x8*)&qbase[32];
    qf[2] = *(const bf16x8*)&qbase[64];
    qf[3] = *(const bf16x8*)&qbase[96];

    f32x4 acc[2][4];
#pragma unroll
    for (int hh = 0; hh < 2; ++hh)
#pragma unroll
      for (int cc = 0; cc < 4; ++cc) acc[hh][cc] = {0.f, 0.f, 0.f, 0.f};

    const unsigned short* vb0 = &Vt[((size_t)((b << 10) + (w << 7)) << 11)];

    for (int ts = s; ts < nt; ts += 4) {
      const int j0 = ts << 6;
      // V chunk A prefetch (hides under K loads + QK + exchange)
      uint2 vlo[2][4], vhi[2][4];
#pragma unroll
      for (int hh = 0; hh < 2; ++hh)
#pragma unroll
        for (int cc = 0; cc < 4; ++cc) {
          const unsigned short* vr =
              &vb0[((size_t)((hh << 6) + (cc << 4) + c) << 11) + j0 + (g << 2)];
          vlo[hh][cc] = *(const uint2*)&vr[0];
          vhi[hh][cc] = *(const uint2*)&vr[16];
        }
      // QK on 4 j-subtiles; exp; psum; pack exp to bf16 (carried across barrier)
      unsigned ep[2][8];  // [hh][2*jt + half]
      f32x4 ps[4];
#pragma unroll
      for (int jt = 0; jt < 4; ++jt) {
        const unsigned short* kbase =
            &Kb[((size_t)((b << 11) + j0 + (jt << 4) + c) << 10) + (w << 7) + (g << 3)];
        f32x4 pst = {0.f, 0.f, 0.f, 0.f};
#pragma unroll
        for (int hh = 0; hh < 2; ++hh) {
          const bf16x8 k0 = *(const bf16x8*)&kbase[hh << 6];
          const bf16x8 k1 = *(const bf16x8*)&kbase[(hh << 6) + 32];
          f32x4 a = {0.f, 0.f, 0.f, 0.f};
          a = __builtin_amdgcn_mfma_f32_16x16x32_bf16(k0, qf[2 * hh], a, 0, 0, 0);
          a = __builtin_amdgcn_mfma_f32_16x16x32_bf16(k1, qf[2 * hh + 1], a, 0, 0, 0);
          const float e0 = exp2f(a[0] * SC), e1 = exp2f(a[1] * SC);
          const float e2 = exp2f(a[2] * SC), e3 = exp2f(a[3] * SC);
          pst[0] += e0; pst[1] += e1; pst[2] += e2; pst[3] += e3;
          ep[hh][2 * jt] = pack_bf16(e0, e1);
          ep[hh][2 * jt + 1] = pack_bf16(e2, e3);
        }
        ps[jt] = pst;
      }
#pragma unroll
      for (int jt = 0; jt < 4; ++jt) Sx[buf][w][jt][l] = ps[jt];
      __syncthreads();
      f32x4 inv[4];
#pragma unroll
      for (int jt = 0; jt < 4; ++jt) {
        f32x4 t = Sx[buf][0][jt][l];
#pragma unroll
        for (int d = 1; d < 8; ++d) t += Sx[buf][d][jt][l];
#pragma unroll
        for (int r = 0; r < 4; ++r) inv[jt][r] = __builtin_amdgcn_rcpf(t[r]);
      }
      buf ^= 1;
      // two 32-j PV chunks
#pragma unroll
      for (int ch = 0; ch < 2; ++ch) {
        if (ch == 1) {
          // V chunk B loads (reuse regs; WAR after PV-A handled by compiler)
#pragma unroll
          for (int hh = 0; hh < 2; ++hh)
#pragma unroll
            for (int cc = 0; cc < 4; ++cc) {
              const unsigned short* vr =
                  &vb0[((size_t)((hh << 6) + (cc << 4) + c) << 11) + j0 + 32 + (g << 2)];
              vlo[hh][cc] = *(const uint2*)&vr[0];
              vhi[hh][cc] = *(const uint2*)&vr[16];
            }
        }
        const int jta = ch << 1, jtb = jta + 1;
        const int jba = j0 + (jta << 4) + (g << 2);
        const int jbb = j0 + (jtb << 4) + (g << 2);
#pragma unroll
        for (int hh = 0; hh < 2; ++hh) {
          float wv[8];
          wv[0] = blo(ep[hh][2 * jta]);
          wv[1] = bhi(ep[hh][2 * jta]);
          wv[2] = blo(ep[hh][2 * jta + 1]);
          wv[3] = bhi(ep[hh][2 * jta + 1]);
          wv[4] = blo(ep[hh][2 * jtb]);
          wv[5] = bhi(ep[hh][2 * jtb]);
          wv[6] = blo(ep[hh][2 * jtb + 1]);
          wv[7] = bhi(ep[hh][2 * jtb + 1]);
#pragma unroll
          for (int r = 0; r < 4; ++r) {
            wv[r] = (jba + r > ib) ? 0.0625f : wv[r] * inv[jta][r];
            wv[4 + r] = (jbb + r > ib) ? 0.0625f : wv[4 + r] * inv[jtb][r];
          }
          union { bf16x8 v; unsigned u[4]; } pa;
          pa.u[0] = pack_bf16(wv[0], wv[1]);
          pa.u[1] = pack_bf16(wv[2], wv[3]);
          pa.u[2] = pack_bf16(wv[4], wv[5]);
          pa.u[3] = pack_bf16(wv[6], wv[7]);
#pragma unroll
          for (int cc = 0; cc < 4; ++cc) {
            union { bf16x8 v; unsigned u[4]; } vf;
            vf.u[0] = vlo[hh][cc].x; vf.u[1] = vlo[hh][cc].y;
            vf.u[2] = vhi[hh][cc].x; vf.u[3] = vhi[hh][cc].y;
            acc[hh][cc] = __builtin_amdgcn_mfma_f32_16x16x32_bf16(pa.v, vf.v, acc[hh][cc], 0, 0, 0);
          }
        }
      }
    }
    // write this tile's strip partial
#pragma unroll
    for (int hh = 0; hh < 2; ++hh)
#pragma unroll
      for (int cc = 0; cc < 4; ++cc) {
        const int d = (w << 7) + (hh << 6) + (cc << 4) + c;
#pragma unroll
        for (int r = 0; r < 4; ++r)
          AOp[((size_t)((b << 11) + i0 + (g << 2) + r) << 10) + d] = f2b(acc[hh][cc][r]);
      }
    __syncthreads();  // Sx safe for next phase
  }
}

// ---------- sum 4 bf16 partials + (1/16)*suffix -> bf16 (64-j coverage granularity) ----------
__global__ __launch_bounds__(256) void aocvt(const unsigned short* __restrict__ P0,
                                             const unsigned short* __restrict__ P1,
                                             const unsigned short* __restrict__ P2,
                                             const unsigned short* __restrict__ P3,
                                             const float* __restrict__ Suf,
                                             unsigned short* __restrict__ AOb) {
  const int i = (blockIdx.x * 256 + threadIdx.x) << 3;
  const int m = i >> 10;
  const int b = m >> 11;
  const int sufidx = (((m & 2047) >> 6) << 1) + 2;  // attn covers j < 64*((i>>6)+1)
  const int d0 = i & 1023;
  const float* sp = &Suf[((size_t)(b * 65 + sufidx) << 10) + d0];
  const uint4 v0 = *(const uint4*)&P0[i];
  const uint4 v1 = *(const uint4*)&P1[i];
  const uint4 v2 = *(const uint4*)&P2[i];
  const uint4 v3 = *(const uint4*)&P3[i];
  const float4 s0 = *(const float4*)&sp[0];
  const float4 s1 = *(const float4*)&sp[4];
  uint4 o;
  o.x = pack_bf16(blo(v0.x) + blo(v1.x) + blo(v2.x) + blo(v3.x) + 0.0625f * s0.x,
                  bhi(v0.x) + bhi(v1.x) + bhi(v2.x) + bhi(v3.x) + 0.0625f * s0.y);
  o.y = pack_bf16(blo(v0.y) + blo(v1.y) + blo(v2.y) + blo(v3.y) + 0.0625f * s0.z,
                  bhi(v0.y) + bhi(v1.y) + bhi(v2.y) + bhi(v3.y) + 0.0625f * s0.w);
  o.z = pack_bf16(blo(v0.z) + blo(v1.z) + blo(v2.z) + blo(v3.z) + 0.0625f * s1.x,
                  bhi(v0.z) + bhi(v1.z) + bhi(v2.z) + bhi(v3.z) + 0.0625f * s1.y);
  o.w = pack_bf16(blo(v0.w) + blo(v1.w) + blo(v2.w) + blo(v3.w) + 0.0625f * s1.z,
                  bhi(v0.w) + bhi(v1.w) + bhi(v2.w) + bhi(v3.w) + 0.0625f * s1.w);
  *(uint4*)&AOb[i] = o;
}

extern "C" void kernel_launch(void* const* d_in, const int* in_sizes, int n_in,
                              void* d_out, int out_size, void* d_ws, size_t ws_size,
                              hipStream_t stream) {
  (void)in_sizes; (void)n_in; (void)out_size; (void)ws_size;
  const float* x = (const float*)d_in[0];
  const float* Wq = (const float*)d_in[1];
  const float* bq = (const float*)d_in[2];
  const float* Wk = (const float*)d_in[3];
  const float* bk = (const float*)d_in[4];
  const float* Wv = (const float*)d_in[5];
  const float* bv = (const float*)d_in[6];
  const float* Wo = (const float*)d_in[7];
  const float* bo = (const float*)d_in[8];
  float* out = (float*)d_out;
  char* ws = (char*)d_ws;

  const size_t MB = 1024 * 1024;
  unsigned short* xb  = (unsigned short*)(ws);            // 0-8MB; = AOP0 after projections
  unsigned short* Qb  = (unsigned short*)(ws + 8 * MB);   // 8-16; = AOb after attn
  unsigned short* Kb  = (unsigned short*)(ws + 16 * MB);  // 16-24
  unsigned short* Vb  = (unsigned short*)(ws + 24 * MB);  // 24-32; = AOP1 after transpose/vblk
  unsigned short* Vt  = (unsigned short*)(ws + 32 * MB);  // 32-40
  unsigned short* Wqt = (unsigned short*)(ws + 40 * MB);  // 40-42; Blk/Suf overlay after proj
  unsigned short* Wkt = (unsigned short*)(ws + 42 * MB);  // 42-44
  unsigned short* Wvt = (unsigned short*)(ws + 44 * MB);  // 44-46
  unsigned short* Wot = (unsigned short*)(ws + 46 * MB);  // 46-48
  unsigned short* AOP2 = (unsigned short*)(ws + 48 * MB); // 48-56
  unsigned short* AOP3 = (unsigned short*)(ws + 56 * MB); // 56-64
  float* Blk = (float*)(ws + 40 * MB);
  float* Suf = (float*)(ws + 40 * MB + 512 * 1024);
  unsigned short* AOP0 = xb;
  unsigned short* AOP1 = Vb;
  unsigned short* AOb = Qb;

  hipLaunchKernelGGL(wtrans, dim3(16, 16, 4), dim3(256), 0, stream,
                     Wq, Wk, Wv, Wo, Wqt, Wkt, Wvt, Wot);
  hipLaunchKernelGGL(xconv, dim3(2048), dim3(256), 0, stream, x, xb);
  hipLaunchKernelGGL((gemm_mfma<true>), dim3(8, 32, 3), dim3(256), 0, stream,
                     xb, Wqt, Wkt, Wvt, bq, bk, bv, (void*)Qb, (void*)Kb, (void*)Vb);
  hipLaunchKernelGGL(transpose_bf16, dim3(32, 16, 2), dim3(256), 0, stream, Vb, Vt);
  hipLaunchKernelGGL(vblk32, dim3(128), dim3(256), 0, stream, Vb, Blk);
  hipLaunchKernelGGL(vsuffix32, dim3(8), dim3(256), 0, stream, Blk, Suf);
  hipLaunchKernelGGL(attn_v10, dim3(4, 64, 2), dim3(512), 0, stream,
                     Qb, Kb, Vt, AOP0, AOP1, AOP2, AOP3);
  hipLaunchKernelGGL(aocvt, dim3(2048), dim3(256), 0, stream,
                     AOP0, AOP1, AOP2, AOP3, Suf, AOb);
  hipLaunchKernelGGL((gemm_mfma<false>), dim3(8, 32, 1), dim3(256), 0, stream,
                     AOb, Wot, Wot, Wot, bo, bo, bo, (void*)out, (void*)out, (void*)out);
}

// Round 11
// 397.423 us; speedup vs baseline: 1.3479x; 1.3479x over previous
//
#include <hip/hip_runtime.h>
#include <hip/hip_bf16.h>

#define B_ 2
#define T_ 2048
#define D_ 1024
#define H_ 16

typedef __attribute__((ext_vector_type(8))) short bf16x8;
typedef __attribute__((ext_vector_type(4))) float f32x4;

__device__ __forceinline__ unsigned pack_bf16(float x, float y) {
  unsigned xb = __float_as_uint(x), yb = __float_as_uint(y);
  xb += 0x7fffu + ((xb >> 16) & 1u);
  yb += 0x7fffu + ((yb >> 16) & 1u);
  return (xb >> 16) | (yb & 0xffff0000u);
}
__device__ __forceinline__ unsigned short f2b(float x) {
  unsigned u = __float_as_uint(x);
  u += 0x7fffu + ((u >> 16) & 1u);
  return (unsigned short)(u >> 16);
}
__device__ __forceinline__ float blo(unsigned u) { return __uint_as_float(u << 16); }
__device__ __forceinline__ float bhi(unsigned u) { return __uint_as_float(u & 0xffff0000u); }

__device__ __forceinline__ void gld_lds16(const unsigned short* g, unsigned short* l) {
  __builtin_amdgcn_global_load_lds(
      (const __attribute__((address_space(1))) unsigned int*)g,
      (__attribute__((address_space(3))) unsigned int*)l, 16, 0, 0);
}

// ---------- weight transpose + convert: Wt[n][k] = bf16(W[k][n]), 4 weights ----------
__global__ __launch_bounds__(256) void wtrans(const float* __restrict__ W0, const float* __restrict__ W1,
                                              const float* __restrict__ W2, const float* __restrict__ W3,
                                              unsigned short* __restrict__ T0, unsigned short* __restrict__ T1,
                                              unsigned short* __restrict__ T2, unsigned short* __restrict__ T3) {
  const int z = blockIdx.z;
  const float* W = z == 0 ? W0 : z == 1 ? W1 : z == 2 ? W2 : W3;
  unsigned short* T = z == 0 ? T0 : z == 1 ? T1 : z == 2 ? T2 : T3;
  __shared__ unsigned short t[64][72];
  const int k0 = blockIdx.x << 6, n0 = blockIdx.y << 6;
  const int r = threadIdx.x >> 2, c16 = (threadIdx.x & 3) << 4;
#pragma unroll
  for (int e = 0; e < 4; ++e) {
    const float4 v = *(const float4*)&W[(size_t)(k0 + r) * 1024 + n0 + c16 + e * 4];
    t[r][c16 + e * 4 + 0] = f2b(v.x);
    t[r][c16 + e * 4 + 1] = f2b(v.y);
    t[r][c16 + e * 4 + 2] = f2b(v.z);
    t[r][c16 + e * 4 + 3] = f2b(v.w);
  }
  __syncthreads();
  unsigned short o[16];
#pragma unroll
  for (int e = 0; e < 16; ++e) o[e] = t[c16 + e][r];
  unsigned short* dst = &T[(size_t)(n0 + r) * 1024 + k0 + c16];
  *(uint4*)&dst[0] = *(uint4*)&o[0];
  *(uint4*)&dst[8] = *(uint4*)&o[8];
}

// ---------- x fp32 -> bf16 ----------
__global__ __launch_bounds__(256) void xconv(const float* __restrict__ x, unsigned short* __restrict__ xb) {
  const int i = (blockIdx.x * 256 + threadIdx.x) * 8;
  const float4 a = *(const float4*)&x[i];
  const float4 b = *(const float4*)&x[i + 4];
  uint4 o;
  o.x = pack_bf16(a.x, a.y);
  o.y = pack_bf16(a.z, a.w);
  o.z = pack_bf16(b.x, b.y);
  o.w = pack_bf16(b.z, b.w);
  *(uint4*)&xb[i] = o;
}

// ---------- bf16 MFMA GEMM: Y = A[M,1024] @ Bt[n][k]^T + bias ----------
template <bool BF16OUT>
__global__ __launch_bounds__(256) void gemm_mfma(const unsigned short* __restrict__ A,
                                                 const unsigned short* __restrict__ B0,
                                                 const unsigned short* __restrict__ B1,
                                                 const unsigned short* __restrict__ B2,
                                                 const float* __restrict__ bi0, const float* __restrict__ bi1,
                                                 const float* __restrict__ bi2,
                                                 void* __restrict__ Y0, void* __restrict__ Y1,
                                                 void* __restrict__ Y2) {
  const int z = blockIdx.z;
  const unsigned short* Bt = z == 0 ? B0 : z == 1 ? B1 : B2;
  const float* bias = z == 0 ? bi0 : z == 1 ? bi1 : bi2;
  void* Y = z == 0 ? Y0 : z == 1 ? Y1 : Y2;
  __shared__ unsigned short As[8192];
  __shared__ unsigned short Bs[8192];
  const int tid = threadIdx.x;
  const int m0 = blockIdx.y << 7, n0 = blockIdx.x << 7;
  const int w = tid >> 6, l = tid & 63, g = l >> 4, c = l & 15;
  const int wm = (w >> 1) << 6, wn = (w & 1) << 6;
  const int srow = tid >> 3;
  const int skel = ((tid & 7) ^ (srow & 7)) << 3;
  const unsigned short* ga = &A[(size_t)(m0 + srow) * 1024 + skel];
  const unsigned short* gb = &Bt[(size_t)(n0 + srow) * 1024 + skel];
  unsigned short* la = &As[tid << 3];
  unsigned short* lb = &Bs[tid << 3];
  f32x4 acc[4][4];
#pragma unroll
  for (int i = 0; i < 4; ++i)
#pragma unroll
    for (int j = 0; j < 4; ++j) acc[i][j] = {0.f, 0.f, 0.f, 0.f};
  for (int k0 = 0; k0 < 1024; k0 += 64) {
    __syncthreads();
#pragma unroll
    for (int a = 0; a < 4; ++a) {
      gld_lds16(ga + (size_t)(a << 5) * 1024 + k0, la + (a << 11));
      gld_lds16(gb + (size_t)(a << 5) * 1024 + k0, lb + (a << 11));
    }
    __syncthreads();
#pragma unroll
    for (int kc = 0; kc < 2; ++kc) {
      bf16x8 af[4], bfr[4];
#pragma unroll
      for (int mf = 0; mf < 4; ++mf) {
        const int m = wm + (mf << 4) + c;
        af[mf] = *(const bf16x8*)&As[((m << 6) + (kc << 5) + (g << 3)) ^ ((m & 7) << 3)];
      }
#pragma unroll
      for (int nf = 0; nf < 4; ++nf) {
        const int n = wn + (nf << 4) + c;
        bfr[nf] = *(const bf16x8*)&Bs[((n << 6) + (kc << 5) + (g << 3)) ^ ((n & 7) << 3)];
      }
#pragma unroll
      for (int mf = 0; mf < 4; ++mf)
#pragma unroll
        for (int nf = 0; nf < 4; ++nf)
          acc[mf][nf] = __builtin_amdgcn_mfma_f32_16x16x32_bf16(af[mf], bfr[nf], acc[mf][nf], 0, 0, 0);
    }
  }
#pragma unroll
  for (int nf = 0; nf < 4; ++nf) {
    const int n = n0 + wn + (nf << 4) + c;
    const float bb = bias[n];
#pragma unroll
    for (int mf = 0; mf < 4; ++mf) {
      const int mrow = m0 + wm + (mf << 4) + (g << 2);
#pragma unroll
      for (int r = 0; r < 4; ++r) {
        const float val = acc[mf][nf][r] + bb;
        if (BF16OUT)
          ((unsigned short*)Y)[((size_t)(mrow + r) << 10) + n] = f2b(val);
        else
          ((float*)Y)[((size_t)(mrow + r) << 10) + n] = val;
      }
    }
  }
}

// ---------- bf16 transpose: Vb [b][t][d] -> Vt [b][d][t] ----------
__global__ __launch_bounds__(256) void transpose_bf16(const unsigned short* __restrict__ Vb,
                                                      unsigned short* __restrict__ Vt) {
  __shared__ unsigned short tile[64][73];
  const int b = blockIdx.z;
  const int t0 = blockIdx.x << 6, d0 = blockIdx.y << 6;
  const int row = threadIdx.x >> 2, cq = (threadIdx.x & 3) << 4;
  const unsigned short* src = &Vb[((size_t)((b << 11) + t0 + row) << 10) + d0 + cq];
  const uint4 va = *(const uint4*)&src[0];
  const uint4 vb2 = *(const uint4*)&src[8];
  const unsigned in[8] = {va.x, va.y, va.z, va.w, vb2.x, vb2.y, vb2.z, vb2.w};
#pragma unroll
  for (int e = 0; e < 8; ++e) {
    tile[row][cq + 2 * e] = (unsigned short)in[e];
    tile[row][cq + 2 * e + 1] = (unsigned short)(in[e] >> 16);
  }
  __syncthreads();
  unsigned o[8];
#pragma unroll
  for (int e = 0; e < 8; ++e)
    o[e] = (unsigned)tile[cq + 2 * e][row] | ((unsigned)tile[cq + 2 * e + 1][row] << 16);
  unsigned short* dst = &Vt[((size_t)((b << 10) + d0 + row) << 11) + t0 + cq];
  uint4 lo, hi;
  lo.x = o[0]; lo.y = o[1]; lo.z = o[2]; lo.w = o[3];
  hi.x = o[4]; hi.y = o[5]; hi.z = o[6]; hi.w = o[7];
  *(uint4*)&dst[0] = lo;
  *(uint4*)&dst[8] = hi;
}

// ---------- per-32-row block sums of V ----------
__global__ __launch_bounds__(256) void vblk32(const unsigned short* __restrict__ Vb,
                                              float* __restrict__ Blk) {
  const int b = blockIdx.x >> 6, t = blockIdx.x & 63;
  const int d4 = threadIdx.x << 2;
  float s0 = 0.f, s1 = 0.f, s2 = 0.f, s3 = 0.f;
  for (int j = 0; j < 32; ++j) {
    const uint2 v = *(const uint2*)&Vb[((size_t)((b << 11) + (t << 5) + j) << 10) + d4];
    s0 += blo(v.x); s1 += bhi(v.x); s2 += blo(v.y); s3 += bhi(v.y);
  }
  float4 o = {s0, s1, s2, s3};
  *(float4*)&Blk[((size_t)((b << 6) + t) << 10) + d4] = o;
}

// ---------- suffix over 64 tiles ----------
__global__ __launch_bounds__(256) void vsuffix32(const float* __restrict__ Blk, float* __restrict__ Suf) {
  const int idx = blockIdx.x * 256 + threadIdx.x;
  const int b = idx >> 10, d = idx & 1023;
  float s = 0.f;
  Suf[((size_t)(b * 65 + 64) << 10) + d] = 0.f;
  for (int t = 63; t >= 0; --t) {
    s += Blk[((size_t)((b << 6) + t) << 10) + d];
    Suf[((size_t)(b * 65 + t) << 10) + d] = s;
  }
}

// ---------- attention v11: softmax-exchange pipelined one step ----------
// v7 grid (4 strips x 128 tiles x 2 b, 4 blocks/CU). Per 32-j step: issue V loads
// (carried one step) -> QK mfma(K,Q) + exp2 + Sigma-write for step t -> THEN, before
// the barrier, LDS-reduce + weights + PV for step t-1 (fenced by previous barrier;
// double-buffered Sx). Reduce+PV hide under K-load latency. Drain after loop.
__global__ __launch_bounds__(512, 4) void attn_v11(const unsigned short* __restrict__ Qb,
                                                   const unsigned short* __restrict__ Kb,
                                                   const unsigned short* __restrict__ Vt,
                                                   unsigned short* __restrict__ P0,
                                                   unsigned short* __restrict__ P1,
                                                   unsigned short* __restrict__ P2,
                                                   unsigned short* __restrict__ P3) {
  __shared__ f32x4 Sx[2][8][2][64];  // 32 KB double-buffered exchange

  const int s = blockIdx.x;
  const int it = 127 - blockIdx.y;  // heavy-first
  const int b = blockIdx.z;
  const int nt = (it + 2) >> 1;
  const int i0 = it << 4;
  const int tid = threadIdx.x;
  const int w = tid >> 6, l = tid & 63, g = l >> 4, c = l & 15;
  const int ib = i0 + c;
  const float SC = 0.04508422f;  // log2(e)/32

  const unsigned short* qbase = &Qb[((size_t)((b << 11) + i0 + c) << 10) + (w << 7) + (g << 3)];
  bf16x8 qf[4];
  qf[0] = *(const bf16x8*)&qbase[0];
  qf[1] = *(const bf16x8*)&qbase[32];
  qf[2] = *(const bf16x8*)&qbase[64];
  qf[3] = *(const bf16x8*)&qbase[96];

  f32x4 acc[2][4];
#pragma unroll
  for (int hh = 0; hh < 2; ++hh)
#pragma unroll
    for (int cc = 0; cc < 4; ++cc) acc[hh][cc] = {0.f, 0.f, 0.f, 0.f};

  const unsigned short* vb0 = &Vt[((size_t)((b << 10) + (w << 7)) << 11)];

  // carried pipeline state (prev step)
  unsigned epP[2][4];
  uint2 vloP[2][4], vhiP[2][4];
  int jbP = 0;
  int buf = 0;

  for (int ts = s; ts < nt; ts += 4) {
    const int j0 = ts << 5;
    // V loads for THIS step (consumed next iteration / drain)
    uint2 vlo[2][4], vhi[2][4];
#pragma unroll
    for (int hh = 0; hh < 2; ++hh)
#pragma unroll
      for (int cc = 0; cc < 4; ++cc) {
        const unsigned short* vr = &vb0[((size_t)((hh << 6) + (cc << 4) + c) << 11) + j0 + (g << 2)];
        vlo[hh][cc] = *(const uint2*)&vr[0];
        vhi[hh][cc] = *(const uint2*)&vr[16];
      }
    // QK + exp + Sigma-write for step t
    unsigned ep[2][4];
    f32x4 ps0 = {0.f, 0.f, 0.f, 0.f}, ps1 = {0.f, 0.f, 0.f, 0.f};
#pragma unroll
    for (int jt = 0; jt < 2; ++jt) {
      const unsigned short* kbase =
          &Kb[((size_t)((b << 11) + j0 + (jt << 4) + c) << 10) + (w << 7) + (g << 3)];
#pragma unroll
      for (int hh = 0; hh < 2; ++hh) {
        const bf16x8 k0 = *(const bf16x8*)&kbase[hh << 6];
        const bf16x8 k1 = *(const bf16x8*)&kbase[(hh << 6) + 32];
        f32x4 a = {0.f, 0.f, 0.f, 0.f};
        a = __builtin_amdgcn_mfma_f32_16x16x32_bf16(k0, qf[2 * hh], a, 0, 0, 0);
        a = __builtin_amdgcn_mfma_f32_16x16x32_bf16(k1, qf[2 * hh + 1], a, 0, 0, 0);
        const float e0 = exp2f(a[0] * SC), e1 = exp2f(a[1] * SC);
        const float e2 = exp2f(a[2] * SC), e3 = exp2f(a[3] * SC);
        if (jt == 0) { ps0[0] += e0; ps0[1] += e1; ps0[2] += e2; ps0[3] += e3; }
        else { ps1[0] += e0; ps1[1] += e1; ps1[2] += e2; ps1[3] += e3; }
        ep[hh][(jt << 1)] = pack_bf16(e0, e1);
        ep[hh][(jt << 1) + 1] = pack_bf16(e2, e3);
      }
    }
    Sx[buf][w][0][l] = ps0;
    Sx[buf][w][1][l] = ps1;
    // PV of PREVIOUS step (before barrier; overlaps this step's load latency)
    if (ts != s) {
      const int pb = buf ^ 1;
      f32x4 s0 = Sx[pb][0][0][l];
      f32x4 s1 = Sx[pb][0][1][l];
#pragma unroll
      for (int d = 1; d < 8; ++d) {
        s0 += Sx[pb][d][0][l];
        s1 += Sx[pb][d][1][l];
      }
      f32x4 inv0, inv1;
#pragma unroll
      for (int r = 0; r < 4; ++r) {
        inv0[r] = __builtin_amdgcn_rcpf(s0[r]);
        inv1[r] = __builtin_amdgcn_rcpf(s1[r]);
      }
#pragma unroll
      for (int hh = 0; hh < 2; ++hh) {
        float w0[4], w1[4];
        w0[0] = blo(epP[hh][0]); w0[1] = bhi(epP[hh][0]);
        w0[2] = blo(epP[hh][1]); w0[3] = bhi(epP[hh][1]);
        w1[0] = blo(epP[hh][2]); w1[1] = bhi(epP[hh][2]);
        w1[2] = blo(epP[hh][3]); w1[3] = bhi(epP[hh][3]);
#pragma unroll
        for (int r = 0; r < 4; ++r) {
          w0[r] = (jbP + r > ib) ? 0.0625f : w0[r] * inv0[r];
          w1[r] = (jbP + 16 + r > ib) ? 0.0625f : w1[r] * inv1[r];
        }
        union { bf16x8 v; unsigned u[4]; } pa;
        pa.u[0] = pack_bf16(w0[0], w0[1]);
        pa.u[1] = pack_bf16(w0[2], w0[3]);
        pa.u[2] = pack_bf16(w1[0], w1[1]);
        pa.u[3] = pack_bf16(w1[2], w1[3]);
#pragma unroll
        for (int cc = 0; cc < 4; ++cc) {
          union { bf16x8 v; unsigned u[4]; } vf;
          vf.u[0] = vloP[hh][cc].x; vf.u[1] = vloP[hh][cc].y;
          vf.u[2] = vhiP[hh][cc].x; vf.u[3] = vhiP[hh][cc].y;
          acc[hh][cc] = __builtin_amdgcn_mfma_f32_16x16x32_bf16(pa.v, vf.v, acc[hh][cc], 0, 0, 0);
        }
      }
    }
    __syncthreads();  // fence Sx[buf] writes of step t
    buf ^= 1;
    // rotate carried state
#pragma unroll
    for (int hh = 0; hh < 2; ++hh) {
      epP[hh][0] = ep[hh][0]; epP[hh][1] = ep[hh][1];
      epP[hh][2] = ep[hh][2]; epP[hh][3] = ep[hh][3];
#pragma unroll
      for (int cc = 0; cc < 4; ++cc) {
        vloP[hh][cc] = vlo[hh][cc];
        vhiP[hh][cc] = vhi[hh][cc];
      }
    }
    jbP = j0 + (g << 2);
  }
  // drain: PV of the final step (its sums are in Sx[buf^1], fenced by last barrier)
  if (s < nt) {
    const int pb = buf ^ 1;
    f32x4 s0 = Sx[pb][0][0][l];
    f32x4 s1 = Sx[pb][0][1][l];
#pragma unroll
    for (int d = 1; d < 8; ++d) {
      s0 += Sx[pb][d][0][l];
      s1 += Sx[pb][d][1][l];
    }
    f32x4 inv0, inv1;
#pragma unroll
    for (int r = 0; r < 4; ++r) {
      inv0[r] = __builtin_amdgcn_rcpf(s0[r]);
      inv1[r] = __builtin_amdgcn_rcpf(s1[r]);
    }
#pragma unroll
    for (int hh = 0; hh < 2; ++hh) {
      float w0[4], w1[4];
      w0[0] = blo(epP[hh][0]); w0[1] = bhi(epP[hh][0]);
      w0[2] = blo(epP[hh][1]); w0[3] = bhi(epP[hh][1]);
      w1[0] = blo(epP[hh][2]); w1[1] = bhi(epP[hh][2]);
      w1[2] = blo(epP[hh][3]); w1[3] = bhi(epP[hh][3]);
#pragma unroll
      for (int r = 0; r < 4; ++r) {
        w0[r] = (jbP + r > ib) ? 0.0625f : w0[r] * inv0[r];
        w1[r] = (jbP + 16 + r > ib) ? 0.0625f : w1[r] * inv1[r];
      }
      union { bf16x8 v; unsigned u[4]; } pa;
      pa.u[0] = pack_bf16(w0[0], w0[1]);
      pa.u[1] = pack_bf16(w0[2], w0[3]);
      pa.u[2] = pack_bf16(w1[0], w1[1]);
      pa.u[3] = pack_bf16(w1[2], w1[3]);
#pragma unroll
      for (int cc = 0; cc < 4; ++cc) {
        union { bf16x8 v; unsigned u[4]; } vf;
        vf.u[0] = vloP[hh][cc].x; vf.u[1] = vloP[hh][cc].y;
        vf.u[2] = vhiP[hh][cc].x; vf.u[3] = vhiP[hh][cc].y;
        acc[hh][cc] = __builtin_amdgcn_mfma_f32_16x16x32_bf16(pa.v, vf.v, acc[hh][cc], 0, 0, 0);
      }
    }
  }
  // write strip partial
  unsigned short* AOp = s == 0 ? P0 : s == 1 ? P1 : s == 2 ? P2 : P3;
#pragma unroll
  for (int hh = 0; hh < 2; ++hh)
#pragma unroll
    for (int cc = 0; cc < 4; ++cc) {
      const int d = (w << 7) + (hh << 6) + (cc << 4) + c;
#pragma unroll
      for (int r = 0; r < 4; ++r)
        AOp[((size_t)((b << 11) + i0 + (g << 2) + r) << 10) + d] = f2b(acc[hh][cc][r]);
    }
}

// ---------- sum 4 bf16 partials + (1/16)*suffix -> bf16 ----------
__global__ __launch_bounds__(256) void aocvt(const unsigned short* __restrict__ P0,
                                             const unsigned short* __restrict__ P1,
                                             const unsigned short* __restrict__ P2,
                                             const unsigned short* __restrict__ P3,
                                             const float* __restrict__ Suf,
                                             unsigned short* __restrict__ AOb) {
  const int i = (blockIdx.x * 256 + threadIdx.x) << 3;
  const int m = i >> 10;
  const int b = m >> 11;
  const int sufidx = ((m & 2047) >> 5) + 1;
  const int d0 = i & 1023;
  const float* sp = &Suf[((size_t)(b * 65 + sufidx) << 10) + d0];
  const uint4 v0 = *(const uint4*)&P0[i];
  const uint4 v1 = *(const uint4*)&P1[i];
  const uint4 v2 = *(const uint4*)&P2[i];
  const uint4 v3 = *(const uint4*)&P3[i];
  const float4 s0 = *(const float4*)&sp[0];
  const float4 s1 = *(const float4*)&sp[4];
  uint4 o;
  o.x = pack_bf16(blo(v0.x) + blo(v1.x) + blo(v2.x) + blo(v3.x) + 0.0625f * s0.x,
                  bhi(v0.x) + bhi(v1.x) + bhi(v2.x) + bhi(v3.x) + 0.0625f * s0.y);
  o.y = pack_bf16(blo(v0.y) + blo(v1.y) + blo(v2.y) + blo(v3.y) + 0.0625f * s0.z,
                  bhi(v0.y) + bhi(v1.y) + bhi(v2.y) + bhi(v3.y) + 0.0625f * s0.w);
  o.z = pack_bf16(blo(v0.z) + blo(v1.z) + blo(v2.z) + blo(v3.z) + 0.0625f * s1.x,
                  bhi(v0.z) + bhi(v1.z) + bhi(v2.z) + bhi(v3.z) + 0.0625f * s1.y);
  o.w = pack_bf16(blo(v0.w) + blo(v1.w) + blo(v2.w) + blo(v3.w) + 0.0625f * s1.z,
                  bhi(v0.w) + bhi(v1.w) + bhi(v2.w) + bhi(v3.w) + 0.0625f * s1.w);
  *(uint4*)&AOb[i] = o;
}

extern "C" void kernel_launch(void* const* d_in, const int* in_sizes, int n_in,
                              void* d_out, int out_size, void* d_ws, size_t ws_size,
                              hipStream_t stream) {
  (void)in_sizes; (void)n_in; (void)out_size; (void)ws_size;
  const float* x = (const float*)d_in[0];
  const float* Wq = (const float*)d_in[1];
  const float* bq = (const float*)d_in[2];
  const float* Wk = (const float*)d_in[3];
  const float* bk = (const float*)d_in[4];
  const float* Wv = (const float*)d_in[5];
  const float* bv = (const float*)d_in[6];
  const float* Wo = (const float*)d_in[7];
  const float* bo = (const float*)d_in[8];
  float* out = (float*)d_out;
  char* ws = (char*)d_ws;

  const size_t MB = 1024 * 1024;
  unsigned short* xb  = (unsigned short*)(ws);            // 0-8MB; = AOP0 after projections
  unsigned short* Qb  = (unsigned short*)(ws + 8 * MB);   // 8-16; = AOb after attn
  unsigned short* Kb  = (unsigned short*)(ws + 16 * MB);  // 16-24
  unsigned short* Vb  = (unsigned short*)(ws + 24 * MB);  // 24-32; = AOP1 after transpose/vblk
  unsigned short* Vt  = (unsigned short*)(ws + 32 * MB);  // 32-40
  unsigned short* Wqt = (unsigned short*)(ws + 40 * MB);  // 40-42; Blk/Suf overlay after proj
  unsigned short* Wkt = (unsigned short*)(ws + 42 * MB);  // 42-44
  unsigned short* Wvt = (unsigned short*)(ws + 44 * MB);  // 44-46
  unsigned short* Wot = (unsigned short*)(ws + 46 * MB);  // 46-48
  unsigned short* AOP2 = (unsigned short*)(ws + 48 * MB); // 48-56
  unsigned short* AOP3 = (unsigned short*)(ws + 56 * MB); // 56-64
  float* Blk = (float*)(ws + 40 * MB);
  float* Suf = (float*)(ws + 40 * MB + 512 * 1024);
  unsigned short* AOP0 = xb;
  unsigned short* AOP1 = Vb;
  unsigned short* AOb = Qb;

  hipLaunchKernelGGL(wtrans, dim3(16, 16, 4), dim3(256), 0, stream,
                     Wq, Wk, Wv, Wo, Wqt, Wkt, Wvt, Wot);
  hipLaunchKernelGGL(xconv, dim3(2048), dim3(256), 0, stream, x, xb);
  hipLaunchKernelGGL((gemm_mfma<true>), dim3(8, 32, 3), dim3(256), 0, stream,
                     xb, Wqt, Wkt, Wvt, bq, bk, bv, (void*)Qb, (void*)Kb, (void*)Vb);
  hipLaunchKernelGGL(transpose_bf16, dim3(32, 16, 2), dim3(256), 0, stream, Vb, Vt);
  hipLaunchKernelGGL(vblk32, dim3(128), dim3(256), 0, stream, Vb, Blk);
  hipLaunchKernelGGL(vsuffix32, dim3(8), dim3(256), 0, stream, Blk, Suf);
  hipLaunchKernelGGL(attn_v11, dim3(4, 128, 2), dim3(512), 0, stream,
                     Qb, Kb, Vt, AOP0, AOP1, AOP2, AOP3);
  hipLaunchKernelGGL(aocvt, dim3(2048), dim3(256), 0, stream,
                     AOP0, AOP1, AOP2, AOP3, Suf, AOb);
  hipLaunchKernelGGL((gemm_mfma<false>), dim3(8, 32, 1), dim3(256), 0, stream,
                     AOb, Wot, Wot, Wot, bo, bo, bo, (void*)out, (void*)out, (void*)out);
}

// Round 12
// 295.461 us; speedup vs baseline: 1.8130x; 1.3451x over previous
//
#include <hip/hip_runtime.h>
#include <hip/hip_bf16.h>

#define B_ 2
#define T_ 2048
#define D_ 1024
#define H_ 16

typedef __attribute__((ext_vector_type(8))) short bf16x8;
typedef __attribute__((ext_vector_type(4))) float f32x4;

__device__ __forceinline__ unsigned pack_bf16(float x, float y) {
  unsigned xb = __float_as_uint(x), yb = __float_as_uint(y);
  xb += 0x7fffu + ((xb >> 16) & 1u);
  yb += 0x7fffu + ((yb >> 16) & 1u);
  return (xb >> 16) | (yb & 0xffff0000u);
}
__device__ __forceinline__ unsigned short f2b(float x) {
  unsigned u = __float_as_uint(x);
  u += 0x7fffu + ((u >> 16) & 1u);
  return (unsigned short)(u >> 16);
}
__device__ __forceinline__ float blo(unsigned u) { return __uint_as_float(u << 16); }
__device__ __forceinline__ float bhi(unsigned u) { return __uint_as_float(u & 0xffff0000u); }

__device__ __forceinline__ void gld_lds16(const unsigned short* g, unsigned short* l) {
  __builtin_amdgcn_global_load_lds(
      (const __attribute__((address_space(1))) unsigned int*)g,
      (__attribute__((address_space(3))) unsigned int*)l, 16, 0, 0);
}

// ---------- weight transpose + convert: Wt[n][k] = bf16(W[k][n]), 4 weights ----------
__global__ __launch_bounds__(256) void wtrans(const float* __restrict__ W0, const float* __restrict__ W1,
                                              const float* __restrict__ W2, const float* __restrict__ W3,
                                              unsigned short* __restrict__ T0, unsigned short* __restrict__ T1,
                                              unsigned short* __restrict__ T2, unsigned short* __restrict__ T3) {
  const int z = blockIdx.z;
  const float* W = z == 0 ? W0 : z == 1 ? W1 : z == 2 ? W2 : W3;
  unsigned short* T = z == 0 ? T0 : z == 1 ? T1 : z == 2 ? T2 : T3;
  __shared__ unsigned short t[64][72];
  const int k0 = blockIdx.x << 6, n0 = blockIdx.y << 6;
  const int r = threadIdx.x >> 2, c16 = (threadIdx.x & 3) << 4;
#pragma unroll
  for (int e = 0; e < 4; ++e) {
    const float4 v = *(const float4*)&W[(size_t)(k0 + r) * 1024 + n0 + c16 + e * 4];
    t[r][c16 + e * 4 + 0] = f2b(v.x);
    t[r][c16 + e * 4 + 1] = f2b(v.y);
    t[r][c16 + e * 4 + 2] = f2b(v.z);
    t[r][c16 + e * 4 + 3] = f2b(v.w);
  }
  __syncthreads();
  unsigned short o[16];
#pragma unroll
  for (int e = 0; e < 16; ++e) o[e] = t[c16 + e][r];
  unsigned short* dst = &T[(size_t)(n0 + r) * 1024 + k0 + c16];
  *(uint4*)&dst[0] = *(uint4*)&o[0];
  *(uint4*)&dst[8] = *(uint4*)&o[8];
}

// ---------- x fp32 -> bf16 ----------
__global__ __launch_bounds__(256) void xconv(const float* __restrict__ x, unsigned short* __restrict__ xb) {
  const int i = (blockIdx.x * 256 + threadIdx.x) * 8;
  const float4 a = *(const float4*)&x[i];
  const float4 b = *(const float4*)&x[i + 4];
  uint4 o;
  o.x = pack_bf16(a.x, a.y);
  o.y = pack_bf16(a.z, a.w);
  o.z = pack_bf16(b.x, b.y);
  o.w = pack_bf16(b.z, b.w);
  *(uint4*)&xb[i] = o;
}

// ---------- bf16 MFMA GEMM: Y = A[M,1024] @ Bt[n][k]^T + bias ----------
template <bool BF16OUT>
__global__ __launch_bounds__(256) void gemm_mfma(const unsigned short* __restrict__ A,
                                                 const unsigned short* __restrict__ B0,
                                                 const unsigned short* __restrict__ B1,
                                                 const unsigned short* __restrict__ B2,
                                                 const float* __restrict__ bi0, const float* __restrict__ bi1,
                                                 const float* __restrict__ bi2,
                                                 void* __restrict__ Y0, void* __restrict__ Y1,
                                                 void* __restrict__ Y2) {
  const int z = blockIdx.z;
  const unsigned short* Bt = z == 0 ? B0 : z == 1 ? B1 : B2;
  const float* bias = z == 0 ? bi0 : z == 1 ? bi1 : bi2;
  void* Y = z == 0 ? Y0 : z == 1 ? Y1 : Y2;
  __shared__ unsigned short As[8192];
  __shared__ unsigned short Bs[8192];
  const int tid = threadIdx.x;
  const int m0 = blockIdx.y << 7, n0 = blockIdx.x << 7;
  const int w = tid >> 6, l = tid & 63, g = l >> 4, c = l & 15;
  const int wm = (w >> 1) << 6, wn = (w & 1) << 6;
  const int srow = tid >> 3;
  const int skel = ((tid & 7) ^ (srow & 7)) << 3;
  const unsigned short* ga = &A[(size_t)(m0 + srow) * 1024 + skel];
  const unsigned short* gb = &Bt[(size_t)(n0 + srow) * 1024 + skel];
  unsigned short* la = &As[tid << 3];
  unsigned short* lb = &Bs[tid << 3];
  f32x4 acc[4][4];
#pragma unroll
  for (int i = 0; i < 4; ++i)
#pragma unroll
    for (int j = 0; j < 4; ++j) acc[i][j] = {0.f, 0.f, 0.f, 0.f};
  for (int k0 = 0; k0 < 1024; k0 += 64) {
    __syncthreads();
#pragma unroll
    for (int a = 0; a < 4; ++a) {
      gld_lds16(ga + (size_t)(a << 5) * 1024 + k0, la + (a << 11));
      gld_lds16(gb + (size_t)(a << 5) * 1024 + k0, lb + (a << 11));
    }
    __syncthreads();
#pragma unroll
    for (int kc = 0; kc < 2; ++kc) {
      bf16x8 af[4], bfr[4];
#pragma unroll
      for (int mf = 0; mf < 4; ++mf) {
        const int m = wm + (mf << 4) + c;
        af[mf] = *(const bf16x8*)&As[((m << 6) + (kc << 5) + (g << 3)) ^ ((m & 7) << 3)];
      }
#pragma unroll
      for (int nf = 0; nf < 4; ++nf) {
        const int n = wn + (nf << 4) + c;
        bfr[nf] = *(const bf16x8*)&Bs[((n << 6) + (kc << 5) + (g << 3)) ^ ((n & 7) << 3)];
      }
#pragma unroll
      for (int mf = 0; mf < 4; ++mf)
#pragma unroll
        for (int nf = 0; nf < 4; ++nf)
          acc[mf][nf] = __builtin_amdgcn_mfma_f32_16x16x32_bf16(af[mf], bfr[nf], acc[mf][nf], 0, 0, 0);
    }
  }
#pragma unroll
  for (int nf = 0; nf < 4; ++nf) {
    const int n = n0 + wn + (nf << 4) + c;
    const float bb = bias[n];
#pragma unroll
    for (int mf = 0; mf < 4; ++mf) {
      const int mrow = m0 + wm + (mf << 4) + (g << 2);
#pragma unroll
      for (int r = 0; r < 4; ++r) {
        const float val = acc[mf][nf][r] + bb;
        if (BF16OUT)
          ((unsigned short*)Y)[((size_t)(mrow + r) << 10) + n] = f2b(val);
        else
          ((float*)Y)[((size_t)(mrow + r) << 10) + n] = val;
      }
    }
  }
}

// ---------- bf16 transpose: Vb [b][t][d] -> Vt [b][d][t] ----------
__global__ __launch_bounds__(256) void transpose_bf16(const unsigned short* __restrict__ Vb,
                                                      unsigned short* __restrict__ Vt) {
  __shared__ unsigned short tile[64][73];
  const int b = blockIdx.z;
  const int t0 = blockIdx.x << 6, d0 = blockIdx.y << 6;
  const int row = threadIdx.x >> 2, cq = (threadIdx.x & 3) << 4;
  const unsigned short* src = &Vb[((size_t)((b << 11) + t0 + row) << 10) + d0 + cq];
  const uint4 va = *(const uint4*)&src[0];
  const uint4 vb2 = *(const uint4*)&src[8];
  const unsigned in[8] = {va.x, va.y, va.z, va.w, vb2.x, vb2.y, vb2.z, vb2.w};
#pragma unroll
  for (int e = 0; e < 8; ++e) {
    tile[row][cq + 2 * e] = (unsigned short)in[e];
    tile[row][cq + 2 * e + 1] = (unsigned short)(in[e] >> 16);
  }
  __syncthreads();
  unsigned o[8];
#pragma unroll
  for (int e = 0; e < 8; ++e)
    o[e] = (unsigned)tile[cq + 2 * e][row] | ((unsigned)tile[cq + 2 * e + 1][row] << 16);
  unsigned short* dst = &Vt[((size_t)((b << 10) + d0 + row) << 11) + t0 + cq];
  uint4 lo, hi;
  lo.x = o[0]; lo.y = o[1]; lo.z = o[2]; lo.w = o[3];
  hi.x = o[4]; hi.y = o[5]; hi.z = o[6]; hi.w = o[7];
  *(uint4*)&dst[0] = lo;
  *(uint4*)&dst[8] = hi;
}

// ---------- per-32-row block sums of V ----------
__global__ __launch_bounds__(256) void vblk32(const unsigned short* __restrict__ Vb,
                                              float* __restrict__ Blk) {
  const int b = blockIdx.x >> 6, t = blockIdx.x & 63;
  const int d4 = threadIdx.x << 2;
  float s0 = 0.f, s1 = 0.f, s2 = 0.f, s3 = 0.f;
  for (int j = 0; j < 32; ++j) {
    const uint2 v = *(const uint2*)&Vb[((size_t)((b << 11) + (t << 5) + j) << 10) + d4];
    s0 += blo(v.x); s1 += bhi(v.x); s2 += blo(v.y); s3 += bhi(v.y);
  }
  float4 o = {s0, s1, s2, s3};
  *(float4*)&Blk[((size_t)((b << 6) + t) << 10) + d4] = o;
}

// ---------- suffix over 64 tiles ----------
__global__ __launch_bounds__(256) void vsuffix32(const float* __restrict__ Blk, float* __restrict__ Suf) {
  const int idx = blockIdx.x * 256 + threadIdx.x;
  const int b = idx >> 10, d = idx & 1023;
  float s = 0.f;
  Suf[((size_t)(b * 65 + 64) << 10) + d] = 0.f;
  for (int t = 63; t >= 0; --t) {
    s += Blk[((size_t)((b << 6) + t) << 10) + d];
    Suf[((size_t)(b * 65 + t) << 10) + d] = s;
  }
}

// ---------- attention v12: XCD-local j-strips ----------
// blockIdx.x = combo (b, strip) in [0,8) -> round-robin pins each combo to one XCD.
// Strip s owns complementary j-eighths {s, 7-s} (2 MB K+V working set -> L2-resident).
// Block handles tile pair (y, 127-y) -> ~16.5 steps/block, constant. 512 blocks = 2/CU.
// Per-step wave code identical to v9 (V prefetch, QK mfma(K,Q), exp2, Sx exchange, PV).
__global__ __launch_bounds__(512, 4) void attn_v12(const unsigned short* __restrict__ Qb,
                                                   const unsigned short* __restrict__ Kb,
                                                   const unsigned short* __restrict__ Vt,
                                                   unsigned short* __restrict__ P0,
                                                   unsigned short* __restrict__ P1,
                                                   unsigned short* __restrict__ P2,
                                                   unsigned short* __restrict__ P3) {
  __shared__ f32x4 Sx[2][8][2][64];  // 32 KB double-buffered exchange

  const int combo = blockIdx.x;
  const int b = combo & 1;
  const int s = combo >> 1;          // strip 0..3 -> eighths {s, 7-s}
  const int y = blockIdx.y;          // 0..63 -> tiles y, 127-y
  const int tid = threadIdx.x;
  const int w = tid >> 6, l = tid & 63, g = l >> 4, c = l & 15;
  const float SC = 0.04508422f;  // log2(e)/32
  unsigned short* AOp = s == 0 ? P0 : s == 1 ? P1 : s == 2 ? P2 : P3;
  const unsigned short* vb0 = &Vt[((size_t)((b << 10) + (w << 7)) << 11)];

  int buf = 0;
#pragma unroll
  for (int half = 0; half < 2; ++half) {
    const int it = half ? (127 - y) : y;
    const int nt = (it + 2) >> 1;
    const int i0 = it << 4;
    const int ib = i0 + c;

    const unsigned short* qbase = &Qb[((size_t)((b << 11) + i0 + c) << 10) + (w << 7) + (g << 3)];
    bf16x8 qf[4];
    qf[0] = *(const bf16x8*)&qbase[0];
    qf[1] = *(const bf16x8*)&qbase[32];
    qf[2] = *(const bf16x8*)&qbase[64];
    qf[3] = *(const bf16x8*)&qbase[96];

    f32x4 acc[2][4];
#pragma unroll
    for (int hh = 0; hh < 2; ++hh)
#pragma unroll
      for (int cc = 0; cc < 4; ++cc) acc[hh][cc] = {0.f, 0.f, 0.f, 0.f};

#pragma unroll
    for (int e8 = 0; e8 < 2; ++e8) {
      const int eh = e8 ? (7 - s) : s;
      const int lo = eh << 3;
      const int hi = (lo + 8) < nt ? (lo + 8) : nt;
      for (int ts = lo; ts < hi; ++ts) {
        const int j0 = ts << 5;
        // V prefetch: latency hides under QK + exp + barrier
        uint2 vlo[2][4], vhi[2][4];
#pragma unroll
        for (int hh = 0; hh < 2; ++hh)
#pragma unroll
          for (int cc = 0; cc < 4; ++cc) {
            const unsigned short* vr =
                &vb0[((size_t)((hh << 6) + (cc << 4) + c) << 11) + j0 + (g << 2)];
            vlo[hh][cc] = *(const uint2*)&vr[0];
            vhi[hh][cc] = *(const uint2*)&vr[16];
          }
        f32x4 ex0[2], ex1[2];
        f32x4 ps0 = {0.f, 0.f, 0.f, 0.f}, ps1 = {0.f, 0.f, 0.f, 0.f};
#pragma unroll
        for (int jt = 0; jt < 2; ++jt) {
          const unsigned short* kbase =
              &Kb[((size_t)((b << 11) + j0 + (jt << 4) + c) << 10) + (w << 7) + (g << 3)];
#pragma unroll
          for (int hh = 0; hh < 2; ++hh) {
            const bf16x8 k0 = *(const bf16x8*)&kbase[hh << 6];
            const bf16x8 k1 = *(const bf16x8*)&kbase[(hh << 6) + 32];
            f32x4 a = {0.f, 0.f, 0.f, 0.f};
            a = __builtin_amdgcn_mfma_f32_16x16x32_bf16(k0, qf[2 * hh], a, 0, 0, 0);
            a = __builtin_amdgcn_mfma_f32_16x16x32_bf16(k1, qf[2 * hh + 1], a, 0, 0, 0);
            f32x4 e;
#pragma unroll
            for (int r = 0; r < 4; ++r) e[r] = exp2f(a[r] * SC);
            if (jt == 0) { ex0[hh] = e; ps0 += e; }
            else { ex1[hh] = e; ps1 += e; }
          }
        }
        Sx[buf][w][0][l] = ps0;
        Sx[buf][w][1][l] = ps1;
        __syncthreads();
        f32x4 s0 = Sx[buf][0][0][l];
        f32x4 s1 = Sx[buf][0][1][l];
#pragma unroll
        for (int d = 1; d < 8; ++d) {
          s0 += Sx[buf][d][0][l];
          s1 += Sx[buf][d][1][l];
        }
        buf ^= 1;
        f32x4 inv0, inv1;
#pragma unroll
        for (int r = 0; r < 4; ++r) {
          inv0[r] = __builtin_amdgcn_rcpf(s0[r]);
          inv1[r] = __builtin_amdgcn_rcpf(s1[r]);
        }
        const int jb = j0 + (g << 2);
#pragma unroll
        for (int hh = 0; hh < 2; ++hh) {
          float w0[4], w1[4];
#pragma unroll
          for (int r = 0; r < 4; ++r) {
            w0[r] = (jb + r > ib) ? 0.0625f : ex0[hh][r] * inv0[r];
            w1[r] = (jb + 16 + r > ib) ? 0.0625f : ex1[hh][r] * inv1[r];
          }
          union { bf16x8 v; unsigned u[4]; } pa;
          pa.u[0] = pack_bf16(w0[0], w0[1]);
          pa.u[1] = pack_bf16(w0[2], w0[3]);
          pa.u[2] = pack_bf16(w1[0], w1[1]);
          pa.u[3] = pack_bf16(w1[2], w1[3]);
#pragma unroll
          for (int cc = 0; cc < 4; ++cc) {
            union { bf16x8 v; unsigned u[4]; } vf;
            vf.u[0] = vlo[hh][cc].x; vf.u[1] = vlo[hh][cc].y;
            vf.u[2] = vhi[hh][cc].x; vf.u[3] = vhi[hh][cc].y;
            acc[hh][cc] = __builtin_amdgcn_mfma_f32_16x16x32_bf16(pa.v, vf.v, acc[hh][cc], 0, 0, 0);
          }
        }
      }
    }
    // write this tile's strip partial
#pragma unroll
    for (int hh = 0; hh < 2; ++hh)
#pragma unroll
      for (int cc = 0; cc < 4; ++cc) {
        const int d = (w << 7) + (hh << 6) + (cc << 4) + c;
#pragma unroll
        for (int r = 0; r < 4; ++r)
          AOp[((size_t)((b << 11) + i0 + (g << 2) + r) << 10) + d] = f2b(acc[hh][cc][r]);
      }
    __syncthreads();  // Sx safe for next half
  }
}

// ---------- sum 4 bf16 partials + (1/16)*suffix -> bf16 ----------
__global__ __launch_bounds__(256) void aocvt(const unsigned short* __restrict__ P0,
                                             const unsigned short* __restrict__ P1,
                                             const unsigned short* __restrict__ P2,
                                             const unsigned short* __restrict__ P3,
                                             const float* __restrict__ Suf,
                                             unsigned short* __restrict__ AOb) {
  const int i = (blockIdx.x * 256 + threadIdx.x) << 3;
  const int m = i >> 10;
  const int b = m >> 11;
  const int sufidx = ((m & 2047) >> 5) + 1;
  const int d0 = i & 1023;
  const float* sp = &Suf[((size_t)(b * 65 + sufidx) << 10) + d0];
  const uint4 v0 = *(const uint4*)&P0[i];
  const uint4 v1 = *(const uint4*)&P1[i];
  const uint4 v2 = *(const uint4*)&P2[i];
  const uint4 v3 = *(const uint4*)&P3[i];
  const float4 s0 = *(const float4*)&sp[0];
  const float4 s1 = *(const float4*)&sp[4];
  uint4 o;
  o.x = pack_bf16(blo(v0.x) + blo(v1.x) + blo(v2.x) + blo(v3.x) + 0.0625f * s0.x,
                  bhi(v0.x) + bhi(v1.x) + bhi(v2.x) + bhi(v3.x) + 0.0625f * s0.y);
  o.y = pack_bf16(blo(v0.y) + blo(v1.y) + blo(v2.y) + blo(v3.y) + 0.0625f * s0.z,
                  bhi(v0.y) + bhi(v1.y) + bhi(v2.y) + bhi(v3.y) + 0.0625f * s0.w);
  o.z = pack_bf16(blo(v0.z) + blo(v1.z) + blo(v2.z) + blo(v3.z) + 0.0625f * s1.x,
                  bhi(v0.z) + bhi(v1.z) + bhi(v2.z) + bhi(v3.z) + 0.0625f * s1.y);
  o.w = pack_bf16(blo(v0.w) + blo(v1.w) + blo(v2.w) + blo(v3.w) + 0.0625f * s1.z,
                  bhi(v0.w) + bhi(v1.w) + bhi(v2.w) + bhi(v3.w) + 0.0625f * s1.w);
  *(uint4*)&AOb[i] = o;
}

extern "C" void kernel_launch(void* const* d_in, const int* in_sizes, int n_in,
                              void* d_out, int out_size, void* d_ws, size_t ws_size,
                              hipStream_t stream) {
  (void)in_sizes; (void)n_in; (void)out_size; (void)ws_size;
  const float* x = (const float*)d_in[0];
  const float* Wq = (const float*)d_in[1];
  const float* bq = (const float*)d_in[2];
  const float* Wk = (const float*)d_in[3];
  const float* bk = (const float*)d_in[4];
  const float* Wv = (const float*)d_in[5];
  const float* bv = (const float*)d_in[6];
  const float* Wo = (const float*)d_in[7];
  const float* bo = (const float*)d_in[8];
  float* out = (float*)d_out;
  char* ws = (char*)d_ws;

  const size_t MB = 1024 * 1024;
  unsigned short* xb  = (unsigned short*)(ws);            // 0-8MB; = AOP0 after projections
  unsigned short* Qb  = (unsigned short*)(ws + 8 * MB);   // 8-16; = AOb after attn
  unsigned short* Kb  = (unsigned short*)(ws + 16 * MB);  // 16-24
  unsigned short* Vb  = (unsigned short*)(ws + 24 * MB);  // 24-32; = AOP1 after transpose/vblk
  unsigned short* Vt  = (unsigned short*)(ws + 32 * MB);  // 32-40
  unsigned short* Wqt = (unsigned short*)(ws + 40 * MB);  // 40-42; Blk/Suf overlay after proj
  unsigned short* Wkt = (unsigned short*)(ws + 42 * MB);  // 42-44
  unsigned short* Wvt = (unsigned short*)(ws + 44 * MB);  // 44-46
  unsigned short* Wot = (unsigned short*)(ws + 46 * MB);  // 46-48
  unsigned short* AOP2 = (unsigned short*)(ws + 48 * MB); // 48-56
  unsigned short* AOP3 = (unsigned short*)(ws + 56 * MB); // 56-64
  float* Blk = (float*)(ws + 40 * MB);
  float* Suf = (float*)(ws + 40 * MB + 512 * 1024);
  unsigned short* AOP0 = xb;
  unsigned short* AOP1 = Vb;
  unsigned short* AOb = Qb;

  hipLaunchKernelGGL(wtrans, dim3(16, 16, 4), dim3(256), 0, stream,
                     Wq, Wk, Wv, Wo, Wqt, Wkt, Wvt, Wot);
  hipLaunchKernelGGL(xconv, dim3(2048), dim3(256), 0, stream, x, xb);
  hipLaunchKernelGGL((gemm_mfma<true>), dim3(8, 32, 3), dim3(256), 0, stream,
                     xb, Wqt, Wkt, Wvt, bq, bk, bv, (void*)Qb, (void*)Kb, (void*)Vb);
  hipLaunchKernelGGL(transpose_bf16, dim3(32, 16, 2), dim3(256), 0, stream, Vb, Vt);
  hipLaunchKernelGGL(vblk32, dim3(128), dim3(256), 0, stream, Vb, Blk);
  hipLaunchKernelGGL(vsuffix32, dim3(8), dim3(256), 0, stream, Blk, Suf);
  hipLaunchKernelGGL(attn_v12, dim3(8, 64, 1), dim3(512), 0, stream,
                     Qb, Kb, Vt, AOP0, AOP1, AOP2, AOP3);
  hipLaunchKernelGGL(aocvt, dim3(2048), dim3(256), 0, stream,
                     AOP0, AOP1, AOP2, AOP3, Suf, AOb);
  hipLaunchKernelGGL((gemm_mfma<false>), dim3(8, 32, 1), dim3(256), 0, stream,
                     AOb, Wot, Wot, Wot, bo, bo, bo, (void*)out, (void*)out, (void*)out);
}